// Round 1
// baseline (158.993 us; speedup 1.0000x reference)
//
#include <hip/hip_runtime.h>
#include <hip/hip_bf16.h>
#include <stdint.h>

#define Bz 2
#define Sz 2048
#define Dz 768
#define Hz 12
#define DHz 64
#define Mz (Bz*Sz)   // 4096

typedef __attribute__((ext_vector_type(4))) float f32x4;
typedef __attribute__((ext_vector_type(8))) short bf16x8;
typedef unsigned short u16;
typedef __attribute__((ext_vector_type(8))) unsigned short u16x8;

__device__ __forceinline__ u16 f2bf(float f) {
  union { float f; uint32_t u; } c; c.f = f;
  uint32_t u = c.u;
  return (u16)((u + 0x7fffu + ((u >> 16) & 1u)) >> 16);
}

#define GLL16(gsrc, ldst) \
  __builtin_amdgcn_global_load_lds((const __attribute__((address_space(1))) void*)(gsrc), \
                                   (__attribute__((address_space(3))) void*)(ldst), 16, 0, 0)

__device__ __forceinline__ f32x4 mfma16(bf16x8 a, bf16x8 b, f32x4 c) {
  return __builtin_amdgcn_mfma_f32_16x16x32_bf16(a, b, c, 0, 0, 0);
}

// ---------------- pre-pass: fp32 -> bf16 ----------------
__global__ void cvt_kernel(const float* __restrict__ src, u16* __restrict__ dst, int n8) {
  int i = blockIdx.x * blockDim.x + threadIdx.x;
  if (i >= n8) return;
  const float4* s4 = (const float4*)src;
  float4 a = s4[(size_t)i * 2];
  float4 b = s4[(size_t)i * 2 + 1];
  u16x8 o;
  o[0] = f2bf(a.x); o[1] = f2bf(a.y); o[2] = f2bf(a.z); o[3] = f2bf(a.w);
  o[4] = f2bf(b.x); o[5] = f2bf(b.y); o[6] = f2bf(b.z); o[7] = f2bf(b.w);
  *(u16x8*)(dst + (size_t)i * 8) = o;
}

// ---------------- pre-pass: W [K][N] fp32 -> Wt [N][K] bf16 ----------------
__global__ void wtrans_kernel(const float* __restrict__ W, u16* __restrict__ Wt) {
  __shared__ float tile[32][33];
  int bx = blockIdx.x * 32, by = blockIdx.y * 32;
  int tx = threadIdx.x & 31, ty = threadIdx.x >> 5;   // 256 threads: ty 0..7
#pragma unroll
  for (int i = 0; i < 32; i += 8)
    tile[ty + i][tx] = W[(size_t)(by + ty + i) * Dz + bx + tx];
  __syncthreads();
#pragma unroll
  for (int i = 0; i < 32; i += 8)
    Wt[(size_t)(bx + ty + i) * Dz + by + tx] = f2bf(tile[tx][ty + i]);
}

// ---------------- GEMM core: C[M][N] = A[M][K] * Wt[N][K]^T + bias ----------------
// mode 0: bf16 out, layout [B,H,S,DH]   (Q, K projections)
// mode 1: bf16 out, layout [B,H,DH,S]   (V projection, transposed)
// mode 2: fp32 out, layout [M][N]       (final output projection)
__device__ __forceinline__ void gemm_core(
    const u16* __restrict__ A, const u16* __restrict__ Wt,
    const float* __restrict__ bias, void* __restrict__ out, int mode,
    u16* As, u16* Bs)
{
  const int tid = threadIdx.x;
  const int wid = tid >> 6, lane = tid & 63;
  const int wm = wid >> 1, wn = wid & 1;
  const int m0 = blockIdx.x * 128, n0 = blockIdx.y * 128;
  const int fq = lane >> 4, fr = lane & 15;

  // staging source offsets (pre-swizzled so linear LDS dest + swizzled read match)
  int aoff[2];
#pragma unroll
  for (int c = 0; c < 2; ++c) {
    int off  = (wid * 2 + c) * 1024 + lane * 16;       // linear byte offset in 8KB tile
    int row  = off >> 6;                               // 64B rows (32 bf16)
    int colb = (off & 63) ^ (((row >> 1) & 3) << 4);   // XOR swizzle, bits 4-5
    aoff[c]  = row * Dz + (colb >> 1);                 // element offset (row stride K=768)
  }

  // fragment read byte-offsets
  int raddr[4], rbaddr[4];
#pragma unroll
  for (int f = 0; f < 4; ++f) {
    int rowA = wm * 64 + f * 16 + fr;
    raddr[f]  = rowA * 64 + ((fq * 16) ^ (((rowA >> 1) & 3) << 4));
    int rowB = wn * 64 + f * 16 + fr;
    rbaddr[f] = rowB * 64 + ((fq * 16) ^ (((rowB >> 1) & 3) << 4));
  }

  f32x4 acc[4][4];
  const f32x4 zero = {0.f, 0.f, 0.f, 0.f};
#pragma unroll
  for (int i = 0; i < 4; ++i)
#pragma unroll
    for (int j = 0; j < 4; ++j) acc[i][j] = zero;

  const u16* Abase = A + (size_t)m0 * Dz;
  const u16* Bbase = Wt + (size_t)n0 * Dz;

  for (int kt = 0; kt < Dz; kt += 32) {
#pragma unroll
    for (int c = 0; c < 2; ++c) {
      GLL16(Abase + kt + aoff[c], (char*)As + (wid * 2 + c) * 1024);
      GLL16(Bbase + kt + aoff[c], (char*)Bs + (wid * 2 + c) * 1024);
    }
    __syncthreads();
    bf16x8 af[4], bf[4];
#pragma unroll
    for (int f = 0; f < 4; ++f) {
      af[f] = *(const bf16x8*)((const char*)As + raddr[f]);
      bf[f] = *(const bf16x8*)((const char*)Bs + rbaddr[f]);
    }
#pragma unroll
    for (int i = 0; i < 4; ++i)
#pragma unroll
      for (int j = 0; j < 4; ++j)
        acc[i][j] = mfma16(af[i], bf[j], acc[i][j]);
    __syncthreads();
  }

  if (mode == 2) {
    float* O = (float*)out;
#pragma unroll
    for (int i = 0; i < 4; ++i) {
      int grow = m0 + wm * 64 + i * 16 + fq * 4;
#pragma unroll
      for (int j = 0; j < 4; ++j) {
        int gcol = n0 + wn * 64 + j * 16 + fr;
        float bv = bias[gcol];
#pragma unroll
        for (int r = 0; r < 4; ++r)
          O[(size_t)(grow + r) * Dz + gcol] = acc[i][j][r] + bv;
      }
    }
  } else {
    u16* O = (u16*)out;
#pragma unroll
    for (int i = 0; i < 4; ++i) {
      int grow = m0 + wm * 64 + i * 16 + fq * 4;
#pragma unroll
      for (int j = 0; j < 4; ++j) {
        int gcol = n0 + wn * 64 + j * 16 + fr;
        float bv = bias[gcol];
        int h = gcol >> 6, dh = gcol & 63;
#pragma unroll
        for (int r = 0; r < 4; ++r) {
          int t = grow + r;
          int b = t >> 11, s = t & 2047;
          float v = acc[i][j][r] + bv;
          if (mode == 0)
            O[((size_t)(b * Hz + h) * Sz + s) * DHz + dh] = f2bf(v);
          else
            O[((size_t)(b * Hz + h) * DHz + dh) * Sz + s] = f2bf(v);
        }
      }
    }
  }
}

__global__ __launch_bounds__(256, 2) void gemm_qkv(
    const u16* __restrict__ qb, const u16* __restrict__ kb, const u16* __restrict__ vb,
    const u16* __restrict__ Wqt, const u16* __restrict__ Wkt, const u16* __restrict__ Wvt,
    const float* __restrict__ bq, const float* __restrict__ bk, const float* __restrict__ bv,
    u16* __restrict__ Qh, u16* __restrict__ Kh, u16* __restrict__ Vt)
{
  __shared__ u16 As[128 * 32];
  __shared__ u16 Bs[128 * 32];
  const u16* A; const u16* W; const float* bias; u16* out; int mode;
  if (blockIdx.z == 0)      { A = qb; W = Wqt; bias = bq; out = Qh; mode = 0; }
  else if (blockIdx.z == 1) { A = kb; W = Wkt; bias = bk; out = Kh; mode = 0; }
  else                      { A = vb; W = Wvt; bias = bv; out = Vt; mode = 1; }
  gemm_core(A, W, bias, out, mode, As, Bs);
}

__global__ __launch_bounds__(256, 2) void gemm_out_k(
    const u16* __restrict__ ctx, const u16* __restrict__ Wot,
    const float* __restrict__ bo, float* __restrict__ out)
{
  __shared__ u16 As[128 * 32];
  __shared__ u16 Bs[128 * 32];
  gemm_core(ctx, Wot, bo, (void*)out, 2, As, Bs);
}

// ---------------- flash attention, causal ----------------
// grid (S/64, B*H), block 256. Each wave owns 16 q-rows.
__global__ __launch_bounds__(256, 2) void attn_kernel(
    const u16* __restrict__ Qh, const u16* __restrict__ Kh,
    const u16* __restrict__ Vt, u16* __restrict__ ctx)
{
  __shared__ u16 Ks[64 * 64];
  __shared__ u16 Vs[64 * 64];
  __shared__ u16 Ps[4 * 16 * 64];
  const int tid = threadIdx.x, wid = tid >> 6, lane = tid & 63;
  const int fq = lane >> 4, fr = lane & 15;
  const int bq = blockIdx.x;
  const int bh = blockIdx.y;
  const int b = bh / Hz, h = bh % Hz;
  const int qbase = bq * 64 + wid * 16;

  // Q fragments (held for the whole kernel)
  const u16* Qg = Qh + ((size_t)bh * Sz + qbase) * DHz;
  bf16x8 aq[2];
#pragma unroll
  for (int kk = 0; kk < 2; ++kk)
    aq[kk] = *(const bf16x8*)(Qg + fr * DHz + kk * 32 + fq * 8);

  const f32x4 zero = {0.f, 0.f, 0.f, 0.f};
  f32x4 o[4];
#pragma unroll
  for (int i = 0; i < 4; ++i) o[i] = zero;
  float m_r[4], l_r[4];
#pragma unroll
  for (int r = 0; r < 4; ++r) { m_r[r] = -1e30f; l_r[r] = 0.f; }

  const u16* Kg = Kh + (size_t)bh * Sz * DHz;
  const u16* Vg = Vt + (size_t)bh * DHz * Sz;
  u16* Pw = Ps + wid * 16 * 64;
  const int nkt = bq + 1;

  for (int kt = 0; kt < nkt; ++kt) {
    __syncthreads();   // previous tile's LDS reads complete
#pragma unroll
    for (int c = 0; c < 2; ++c) {
      int off  = (wid * 2 + c) * 1024 + lane * 16;
      int row  = off >> 7;                       // 128B rows (64 bf16)
      int colb = (off & 127) ^ ((row & 7) << 4); // XOR swizzle bits 4-6
      GLL16(Kg + ((size_t)(kt * 64 + row)) * DHz + (colb >> 1), (char*)Ks + (wid * 2 + c) * 1024);
      GLL16(Vg + (size_t)row * Sz + kt * 64 + (colb >> 1),      (char*)Vs + (wid * 2 + c) * 1024);
    }
    __syncthreads();

    // S = Q K^T
    f32x4 s[4];
#pragma unroll
    for (int j = 0; j < 4; ++j) s[j] = zero;
#pragma unroll
    for (int j = 0; j < 4; ++j) {
      int rowK = j * 16 + fr;
#pragma unroll
      for (int kk = 0; kk < 2; ++kk) {
        int cb = (kk * 64 + fq * 16) ^ ((rowK & 7) << 4);
        bf16x8 bk_ = *(const bf16x8*)((const char*)Ks + rowK * 128 + cb);
        s[j] = mfma16(aq[kk], bk_, s[j]);
      }
    }

    // scale + causal mask + row max
    float mt[4];
#pragma unroll
    for (int r = 0; r < 4; ++r) mt[r] = -1e30f;
#pragma unroll
    for (int j = 0; j < 4; ++j) {
      int keyg = kt * 64 + j * 16 + fr;
#pragma unroll
      for (int r = 0; r < 4; ++r) {
        float sv = s[j][r] * 0.125f;
        sv = (keyg <= qbase + fq * 4 + r) ? sv : -1e30f;
        s[j][r] = sv;
        mt[r] = fmaxf(mt[r], sv);
      }
    }
#pragma unroll
    for (int msk = 1; msk < 16; msk <<= 1)
#pragma unroll
      for (int r = 0; r < 4; ++r) mt[r] = fmaxf(mt[r], __shfl_xor(mt[r], msk));

    float alpha[4], rs[4];
#pragma unroll
    for (int r = 0; r < 4; ++r) {
      float mn = fmaxf(m_r[r], mt[r]);
      alpha[r] = __expf(m_r[r] - mn);
      m_r[r] = mn;
      rs[r] = 0.f;
    }

    // P = exp(S - m), write to per-wave LDS (swizzled)
#pragma unroll
    for (int j = 0; j < 4; ++j) {
#pragma unroll
      for (int r = 0; r < 4; ++r) {
        float e = __expf(s[j][r] - m_r[r]);
        rs[r] += e;
        int qr = fq * 4 + r;
        int key2 = (j * 16 + fr) * 2;
        *(u16*)((char*)Pw + qr * 128 + (key2 ^ ((qr & 7) << 4))) = f2bf(e);
      }
    }
#pragma unroll
    for (int msk = 1; msk < 16; msk <<= 1)
#pragma unroll
      for (int r = 0; r < 4; ++r) rs[r] += __shfl_xor(rs[r], msk);
#pragma unroll
    for (int r = 0; r < 4; ++r) l_r[r] = l_r[r] * alpha[r] + rs[r];
#pragma unroll
    for (int i = 0; i < 4; ++i)
#pragma unroll
      for (int r = 0; r < 4; ++r) o[i][r] *= alpha[r];

    // O += P V
#pragma unroll
    for (int kk = 0; kk < 2; ++kk) {
      int cbP = (kk * 64 + fq * 16) ^ ((fr & 7) << 4);
      bf16x8 pa = *(const bf16x8*)((const char*)Pw + fr * 128 + cbP);
#pragma unroll
      for (int fo = 0; fo < 4; ++fo) {
        int rowV = fo * 16 + fr;
        int cbV = (kk * 64 + fq * 16) ^ ((rowV & 7) << 4);
        bf16x8 bv_ = *(const bf16x8*)((const char*)Vs + rowV * 128 + cbV);
        o[fo] = mfma16(pa, bv_, o[fo]);
      }
    }
  }

  // normalize + write ctx [B,S,D] bf16
#pragma unroll
  for (int fo = 0; fo < 4; ++fo) {
    int dh = fo * 16 + fr;
#pragma unroll
    for (int r = 0; r < 4; ++r) {
      int qg = qbase + fq * 4 + r;
      ctx[((size_t)b * Sz + qg) * Dz + h * DHz + dh] = f2bf(o[fo][r] / l_r[r]);
    }
  }
}

// ---------------- launch ----------------
extern "C" void kernel_launch(void* const* d_in, const int* in_sizes, int n_in,
                              void* d_out, int out_size, void* d_ws, size_t ws_size,
                              hipStream_t stream) {
  const float* q  = (const float*)d_in[0];
  const float* k  = (const float*)d_in[1];
  const float* v  = (const float*)d_in[2];
  const float* Wq = (const float*)d_in[3];
  const float* bq = (const float*)d_in[4];
  const float* Wk = (const float*)d_in[5];
  const float* bk = (const float*)d_in[6];
  const float* Wv = (const float*)d_in[7];
  const float* bv = (const float*)d_in[8];
  const float* Wo = (const float*)d_in[9];
  const float* bo = (const float*)d_in[10];
  float* out = (float*)d_out;

  char* ws = (char*)d_ws;
  size_t off = 0;
  auto alloc = [&](size_t bytes) {
    void* p = ws + off;
    off += (bytes + 255) & ~(size_t)255;
    return p;
  };
  u16* qb  = (u16*)alloc((size_t)Mz * Dz * 2);
  u16* kb  = (u16*)alloc((size_t)Mz * Dz * 2);
  u16* vb  = (u16*)alloc((size_t)Mz * Dz * 2);
  u16* Wqt = (u16*)alloc((size_t)Dz * Dz * 2);
  u16* Wkt = (u16*)alloc((size_t)Dz * Dz * 2);
  u16* Wvt = (u16*)alloc((size_t)Dz * Dz * 2);
  u16* Wot = (u16*)alloc((size_t)Dz * Dz * 2);
  u16* Qh  = (u16*)alloc((size_t)Bz * Hz * Sz * DHz * 2);
  u16* Kh  = (u16*)alloc((size_t)Bz * Hz * Sz * DHz * 2);
  u16* Vtr = (u16*)alloc((size_t)Bz * Hz * DHz * Sz * 2);
  u16* ctx = (u16*)alloc((size_t)Mz * Dz * 2);

  int n8 = Mz * Dz / 8;
  int cblk = (n8 + 255) / 256;
  cvt_kernel<<<cblk, 256, 0, stream>>>(q, qb, n8);
  cvt_kernel<<<cblk, 256, 0, stream>>>(k, kb, n8);
  cvt_kernel<<<cblk, 256, 0, stream>>>(v, vb, n8);

  dim3 tg(Dz / 32, Dz / 32);
  wtrans_kernel<<<tg, 256, 0, stream>>>(Wq, Wqt);
  wtrans_kernel<<<tg, 256, 0, stream>>>(Wk, Wkt);
  wtrans_kernel<<<tg, 256, 0, stream>>>(Wv, Wvt);
  wtrans_kernel<<<tg, 256, 0, stream>>>(Wo, Wot);

  gemm_qkv<<<dim3(Mz / 128, Dz / 128, 3), 256, 0, stream>>>(
      qb, kb, vb, Wqt, Wkt, Wvt, bq, bk, bv, Qh, Kh, Vtr);

  attn_kernel<<<dim3(Sz / 64, Bz * Hz), 256, 0, stream>>>(Qh, Kh, Vtr, ctx);

  gemm_out_k<<<dim3(Mz / 128, Dz / 128), 256, 0, stream>>>(ctx, Wot, bo, out);
}

// Round 2
// 154.066 us; speedup vs baseline: 1.0320x; 1.0320x over previous
//
#include <hip/hip_runtime.h>
#include <hip/hip_bf16.h>
#include <stdint.h>

#define Bz 2
#define Sz 2048
#define Dz 768
#define Hz 12
#define DHz 64
#define Mz (Bz*Sz)   // 4096

typedef __attribute__((ext_vector_type(4))) float f32x4;
typedef __attribute__((ext_vector_type(8))) short bf16x8;
typedef unsigned short u16;
typedef __attribute__((ext_vector_type(8))) unsigned short u16x8;

__device__ __forceinline__ u16 f2bf(float f) {
  union { float f; uint32_t u; } c; c.f = f;
  uint32_t u = c.u;
  return (u16)((u + 0x7fffu + ((u >> 16) & 1u)) >> 16);
}

#define GLL16(gsrc, ldst) \
  __builtin_amdgcn_global_load_lds((const __attribute__((address_space(1))) void*)(gsrc), \
                                   (__attribute__((address_space(3))) void*)(ldst), 16, 0, 0)

__device__ __forceinline__ f32x4 mfma16(bf16x8 a, bf16x8 b, f32x4 c) {
  return __builtin_amdgcn_mfma_f32_16x16x32_bf16(a, b, c, 0, 0, 0);
}

// ---------------- pre-pass: fp32 -> bf16 ----------------
__global__ void cvt_kernel(const float* __restrict__ src, u16* __restrict__ dst, int n8) {
  int i = blockIdx.x * blockDim.x + threadIdx.x;
  if (i >= n8) return;
  const float4* s4 = (const float4*)src;
  float4 a = s4[(size_t)i * 2];
  float4 b = s4[(size_t)i * 2 + 1];
  u16x8 o;
  o[0] = f2bf(a.x); o[1] = f2bf(a.y); o[2] = f2bf(a.z); o[3] = f2bf(a.w);
  o[4] = f2bf(b.x); o[5] = f2bf(b.y); o[6] = f2bf(b.z); o[7] = f2bf(b.w);
  *(u16x8*)(dst + (size_t)i * 8) = o;
}

// ---------------- pre-pass: W [K][N] fp32 -> Wt [N][K] bf16 ----------------
__global__ void wtrans_kernel(const float* __restrict__ W, u16* __restrict__ Wt) {
  __shared__ float tile[32][33];
  int bx = blockIdx.x * 32, by = blockIdx.y * 32;
  int tx = threadIdx.x & 31, ty = threadIdx.x >> 5;   // 256 threads: ty 0..7
#pragma unroll
  for (int i = 0; i < 32; i += 8)
    tile[ty + i][tx] = W[(size_t)(by + ty + i) * Dz + bx + tx];
  __syncthreads();
#pragma unroll
  for (int i = 0; i < 32; i += 8)
    Wt[(size_t)(bx + ty + i) * Dz + by + tx] = f2bf(tile[tx][ty + i]);
}

// ---------------- GEMM core: C[M][N] = A[M][K] * Wt[N][K]^T + bias ----------------
// mode 0: bf16 out, layout [B,H,S,DH]   (Q, K projections)  (out = (acc+bias)*oscale)
// mode 1: bf16 out, layout [B,H,DH,S]   (V projection, transposed)
// mode 2: fp32 out, layout [M][N]       (final output projection)
__device__ __forceinline__ void gemm_core(
    const u16* __restrict__ A, const u16* __restrict__ Wt,
    const float* __restrict__ bias, void* __restrict__ out, int mode, float oscale,
    u16* As, u16* Bs)
{
  const int tid = threadIdx.x;
  const int wid = tid >> 6, lane = tid & 63;
  const int wm = wid >> 1, wn = wid & 1;
  const int m0 = blockIdx.x * 128, n0 = blockIdx.y * 128;
  const int fq = lane >> 4, fr = lane & 15;

  // staging source offsets (pre-swizzled so linear LDS dest + swizzled read match)
  int aoff[2];
#pragma unroll
  for (int c = 0; c < 2; ++c) {
    int off  = (wid * 2 + c) * 1024 + lane * 16;       // linear byte offset in 8KB tile
    int row  = off >> 6;                               // 64B rows (32 bf16)
    int colb = (off & 63) ^ (((row >> 1) & 3) << 4);   // XOR swizzle, bits 4-5
    aoff[c]  = row * Dz + (colb >> 1);                 // element offset (row stride K=768)
  }

  // fragment read byte-offsets
  int raddr[4], rbaddr[4];
#pragma unroll
  for (int f = 0; f < 4; ++f) {
    int rowA = wm * 64 + f * 16 + fr;
    raddr[f]  = rowA * 64 + ((fq * 16) ^ (((rowA >> 1) & 3) << 4));
    int rowB = wn * 64 + f * 16 + fr;
    rbaddr[f] = rowB * 64 + ((fq * 16) ^ (((rowB >> 1) & 3) << 4));
  }

  f32x4 acc[4][4];
  const f32x4 zero = {0.f, 0.f, 0.f, 0.f};
#pragma unroll
  for (int i = 0; i < 4; ++i)
#pragma unroll
    for (int j = 0; j < 4; ++j) acc[i][j] = zero;

  const u16* Abase = A + (size_t)m0 * Dz;
  const u16* Bbase = Wt + (size_t)n0 * Dz;

  for (int kt = 0; kt < Dz; kt += 32) {
#pragma unroll
    for (int c = 0; c < 2; ++c) {
      GLL16(Abase + kt + aoff[c], (char*)As + (wid * 2 + c) * 1024);
      GLL16(Bbase + kt + aoff[c], (char*)Bs + (wid * 2 + c) * 1024);
    }
    __syncthreads();
    bf16x8 af[4], bf[4];
#pragma unroll
    for (int f = 0; f < 4; ++f) {
      af[f] = *(const bf16x8*)((const char*)As + raddr[f]);
      bf[f] = *(const bf16x8*)((const char*)Bs + rbaddr[f]);
    }
#pragma unroll
    for (int i = 0; i < 4; ++i)
#pragma unroll
      for (int j = 0; j < 4; ++j)
        acc[i][j] = mfma16(af[i], bf[j], acc[i][j]);
    __syncthreads();
  }

  if (mode == 2) {
    float* O = (float*)out;
#pragma unroll
    for (int i = 0; i < 4; ++i) {
      int grow = m0 + wm * 64 + i * 16 + fq * 4;
#pragma unroll
      for (int j = 0; j < 4; ++j) {
        int gcol = n0 + wn * 64 + j * 16 + fr;
        float bv = bias[gcol];
#pragma unroll
        for (int r = 0; r < 4; ++r)
          O[(size_t)(grow + r) * Dz + gcol] = acc[i][j][r] + bv;
      }
    }
  } else {
    u16* O = (u16*)out;
#pragma unroll
    for (int i = 0; i < 4; ++i) {
      int grow = m0 + wm * 64 + i * 16 + fq * 4;
#pragma unroll
      for (int j = 0; j < 4; ++j) {
        int gcol = n0 + wn * 64 + j * 16 + fr;
        float bv = bias[gcol];
        int h = gcol >> 6, dh = gcol & 63;
#pragma unroll
        for (int r = 0; r < 4; ++r) {
          int t = grow + r;
          int b = t >> 11, s = t & 2047;
          float v = (acc[i][j][r] + bv) * oscale;
          if (mode == 0)
            O[((size_t)(b * Hz + h) * Sz + s) * DHz + dh] = f2bf(v);
          else
            O[((size_t)(b * Hz + h) * DHz + dh) * Sz + s] = f2bf(v);
        }
      }
    }
  }
}

// Q is pre-scaled by 1/sqrt(DH) * log2(e) so attention can use raw v_exp_f32 (exp2)
#define QSCALE 0.1803368801111404f   // 0.125 * 1.4426950408889634

__global__ __launch_bounds__(256, 2) void gemm_qkv(
    const u16* __restrict__ qb, const u16* __restrict__ kb, const u16* __restrict__ vb,
    const u16* __restrict__ Wqt, const u16* __restrict__ Wkt, const u16* __restrict__ Wvt,
    const float* __restrict__ bq, const float* __restrict__ bk, const float* __restrict__ bv,
    u16* __restrict__ Qh, u16* __restrict__ Kh, u16* __restrict__ Vt)
{
  __shared__ u16 As[128 * 32];
  __shared__ u16 Bs[128 * 32];
  const u16* A; const u16* W; const float* bias; u16* out; int mode; float osc;
  if (blockIdx.z == 0)      { A = qb; W = Wqt; bias = bq; out = Qh; mode = 0; osc = QSCALE; }
  else if (blockIdx.z == 1) { A = kb; W = Wkt; bias = bk; out = Kh; mode = 0; osc = 1.f; }
  else                      { A = vb; W = Wvt; bias = bv; out = Vt; mode = 1; osc = 1.f; }
  gemm_core(A, W, bias, out, mode, osc, As, Bs);
}

__global__ __launch_bounds__(256, 2) void gemm_out_k(
    const u16* __restrict__ ctx, const u16* __restrict__ Wot,
    const float* __restrict__ bo, float* __restrict__ out)
{
  __shared__ u16 As[128 * 32];
  __shared__ u16 Bs[128 * 32];
  gemm_core(ctx, Wot, bo, (void*)out, 2, 1.f, As, Bs);
}

// ---------------- flash attention, causal ----------------
// grid (S/64, B*H), block 256. Each wave owns 16 q-rows. K/V double-buffered.
__device__ __forceinline__ void stage_kv(const u16* __restrict__ Kg, const u16* __restrict__ Vg,
                                         int kt, u16* Ks, u16* Vs, int wid, int lane) {
#pragma unroll
  for (int c = 0; c < 2; ++c) {
    int off  = (wid * 2 + c) * 1024 + lane * 16;
    int row  = off >> 7;                       // 128B rows (64 bf16)
    int colb = (off & 127) ^ ((row & 7) << 4); // XOR swizzle bits 4-6
    GLL16(Kg + ((size_t)(kt * 64 + row)) * DHz + (colb >> 1), (char*)Ks + (wid * 2 + c) * 1024);
    GLL16(Vg + (size_t)row * Sz + kt * 64 + (colb >> 1),      (char*)Vs + (wid * 2 + c) * 1024);
  }
}

__global__ __launch_bounds__(256, 2) void attn_kernel(
    const u16* __restrict__ Qh, const u16* __restrict__ Kh,
    const u16* __restrict__ Vt, u16* __restrict__ ctx)
{
  __shared__ u16 Ks[2][64 * 64];
  __shared__ u16 Vs[2][64 * 64];
  __shared__ u16 Ps[4 * 16 * 64];
  const int tid = threadIdx.x, wid = tid >> 6, lane = tid & 63;
  const int fq = lane >> 4, fr = lane & 15;
  const int bq = (gridDim.x - 1) - blockIdx.x;   // heavy blocks dispatch first
  const int bh = blockIdx.y;
  const int b = bh / Hz, h = bh % Hz;
  const int qbase = bq * 64 + wid * 16;

  // Q fragments (held for the whole kernel; pre-scaled by QSCALE at projection)
  const u16* Qg = Qh + ((size_t)bh * Sz + qbase) * DHz;
  bf16x8 aq[2];
#pragma unroll
  for (int kk = 0; kk < 2; ++kk)
    aq[kk] = *(const bf16x8*)(Qg + fr * DHz + kk * 32 + fq * 8);

  const f32x4 zero = {0.f, 0.f, 0.f, 0.f};
  f32x4 o[4];
#pragma unroll
  for (int i = 0; i < 4; ++i) o[i] = zero;
  float m_r[4], l_r[4];
#pragma unroll
  for (int r = 0; r < 4; ++r) { m_r[r] = -1e30f; l_r[r] = 0.f; }

  const u16* Kg = Kh + (size_t)bh * Sz * DHz;
  const u16* Vg = Vt + (size_t)bh * DHz * Sz;
  u16* Pw = Ps + wid * 16 * 64;
  const int nkt = bq + 1;

  stage_kv(Kg, Vg, 0, Ks[0], Vs[0], wid, lane);
  int cur = 0;

  for (int kt = 0; kt < nkt; ++kt) {
    __syncthreads();   // buf[cur] staging drained; prev tile's LDS reads complete
    if (kt + 1 < nkt)
      stage_kv(Kg, Vg, kt + 1, Ks[cur ^ 1], Vs[cur ^ 1], wid, lane);

    const char* Kb = (const char*)Ks[cur];
    const char* Vb = (const char*)Vs[cur];

    // S = Q K^T   (already in log2-domain: Q pre-scaled by 0.125*log2e)
    f32x4 s[4];
#pragma unroll
    for (int j = 0; j < 4; ++j) s[j] = zero;
#pragma unroll
    for (int j = 0; j < 4; ++j) {
      int rowK = j * 16 + fr;
#pragma unroll
      for (int kk = 0; kk < 2; ++kk) {
        int cb = (kk * 64 + fq * 16) ^ ((rowK & 7) << 4);
        bf16x8 bk_ = *(const bf16x8*)(Kb + rowK * 128 + cb);
        s[j] = mfma16(aq[kk], bk_, s[j]);
      }
    }

    // causal mask: only the diagonal tile needs it (block-uniform branch)
    if (kt == bq) {
#pragma unroll
      for (int j = 0; j < 4; ++j) {
        int keyg = kt * 64 + j * 16 + fr;
#pragma unroll
        for (int r = 0; r < 4; ++r)
          if (keyg > qbase + fq * 4 + r) s[j][r] = -1e30f;
      }
    }

    // row max (16-lane butterfly within fr groups)
    float mt[4];
#pragma unroll
    for (int r = 0; r < 4; ++r) mt[r] = s[0][r];
#pragma unroll
    for (int j = 1; j < 4; ++j)
#pragma unroll
      for (int r = 0; r < 4; ++r) mt[r] = fmaxf(mt[r], s[j][r]);
#pragma unroll
    for (int msk = 1; msk < 16; msk <<= 1)
#pragma unroll
      for (int r = 0; r < 4; ++r) mt[r] = fmaxf(mt[r], __shfl_xor(mt[r], msk));

    // defer-max (T13, THR=8 in exp2 domain): rescale only when max grew enough
    int nd = 0;
#pragma unroll
    for (int r = 0; r < 4; ++r) nd |= (mt[r] > m_r[r] + 8.f) ? 1 : 0;
    if (__any(nd)) {
#pragma unroll
      for (int r = 0; r < 4; ++r) {
        float mn = fmaxf(m_r[r], mt[r]);
        float alpha = __builtin_amdgcn_exp2f(m_r[r] - mn);
        m_r[r] = mn;
        l_r[r] *= alpha;
#pragma unroll
        for (int i = 0; i < 4; ++i) o[i][r] *= alpha;
      }
    }

    // P = exp2(S - m), write to per-wave LDS (swizzled)
    float rs[4];
#pragma unroll
    for (int r = 0; r < 4; ++r) rs[r] = 0.f;
#pragma unroll
    for (int j = 0; j < 4; ++j) {
#pragma unroll
      for (int r = 0; r < 4; ++r) {
        float e = __builtin_amdgcn_exp2f(s[j][r] - m_r[r]);
        rs[r] += e;
        int qr = fq * 4 + r;
        int key2 = (j * 16 + fr) * 2;
        *(u16*)((char*)Pw + qr * 128 + (key2 ^ ((qr & 7) << 4))) = f2bf(e);
      }
    }
#pragma unroll
    for (int msk = 1; msk < 16; msk <<= 1)
#pragma unroll
      for (int r = 0; r < 4; ++r) rs[r] += __shfl_xor(rs[r], msk);
#pragma unroll
    for (int r = 0; r < 4; ++r) l_r[r] += rs[r];

    // O += P V
#pragma unroll
    for (int kk = 0; kk < 2; ++kk) {
      int cbP = (kk * 64 + fq * 16) ^ ((fr & 7) << 4);
      bf16x8 pa = *(const bf16x8*)((const char*)Pw + fr * 128 + cbP);
#pragma unroll
      for (int fo = 0; fo < 4; ++fo) {
        int rowV = fo * 16 + fr;
        int cbV = (kk * 64 + fq * 16) ^ ((rowV & 7) << 4);
        bf16x8 bv_ = *(const bf16x8*)(Vb + rowV * 128 + cbV);
        o[fo] = mfma16(pa, bv_, o[fo]);
      }
    }
    cur ^= 1;
  }

  // normalize + write ctx [B,S,D] bf16
#pragma unroll
  for (int fo = 0; fo < 4; ++fo) {
    int dh = fo * 16 + fr;
#pragma unroll
    for (int r = 0; r < 4; ++r) {
      int qg = qbase + fq * 4 + r;
      ctx[((size_t)b * Sz + qg) * Dz + h * DHz + dh] = f2bf(o[fo][r] / l_r[r]);
    }
  }
}

// ---------------- launch ----------------
extern "C" void kernel_launch(void* const* d_in, const int* in_sizes, int n_in,
                              void* d_out, int out_size, void* d_ws, size_t ws_size,
                              hipStream_t stream) {
  const float* q  = (const float*)d_in[0];
  const float* k  = (const float*)d_in[1];
  const float* v  = (const float*)d_in[2];
  const float* Wq = (const float*)d_in[3];
  const float* bq = (const float*)d_in[4];
  const float* Wk = (const float*)d_in[5];
  const float* bk = (const float*)d_in[6];
  const float* Wv = (const float*)d_in[7];
  const float* bv = (const float*)d_in[8];
  const float* Wo = (const float*)d_in[9];
  const float* bo = (const float*)d_in[10];
  float* out = (float*)d_out;

  char* ws = (char*)d_ws;
  size_t off = 0;
  auto alloc = [&](size_t bytes) {
    void* p = ws + off;
    off += (bytes + 255) & ~(size_t)255;
    return p;
  };
  u16* qb  = (u16*)alloc((size_t)Mz * Dz * 2);
  u16* kb  = (u16*)alloc((size_t)Mz * Dz * 2);
  u16* vb  = (u16*)alloc((size_t)Mz * Dz * 2);
  u16* Wqt = (u16*)alloc((size_t)Dz * Dz * 2);
  u16* Wkt = (u16*)alloc((size_t)Dz * Dz * 2);
  u16* Wvt = (u16*)alloc((size_t)Dz * Dz * 2);
  u16* Wot = (u16*)alloc((size_t)Dz * Dz * 2);
  u16* Qh  = (u16*)alloc((size_t)Bz * Hz * Sz * DHz * 2);
  u16* Kh  = (u16*)alloc((size_t)Bz * Hz * Sz * DHz * 2);
  u16* Vtr = (u16*)alloc((size_t)Bz * Hz * DHz * Sz * 2);
  u16* ctx = (u16*)alloc((size_t)Mz * Dz * 2);

  int n8 = Mz * Dz / 8;
  int cblk = (n8 + 255) / 256;
  cvt_kernel<<<cblk, 256, 0, stream>>>(q, qb, n8);
  cvt_kernel<<<cblk, 256, 0, stream>>>(k, kb, n8);
  cvt_kernel<<<cblk, 256, 0, stream>>>(v, vb, n8);

  dim3 tg(Dz / 32, Dz / 32);
  wtrans_kernel<<<tg, 256, 0, stream>>>(Wq, Wqt);
  wtrans_kernel<<<tg, 256, 0, stream>>>(Wk, Wkt);
  wtrans_kernel<<<tg, 256, 0, stream>>>(Wv, Wvt);
  wtrans_kernel<<<tg, 256, 0, stream>>>(Wo, Wot);

  gemm_qkv<<<dim3(Mz / 128, Dz / 128, 3), 256, 0, stream>>>(
      qb, kb, vb, Wqt, Wkt, Wvt, bq, bk, bv, Qh, Kh, Vtr);

  attn_kernel<<<dim3(Sz / 64, Bz * Hz), 256, 0, stream>>>(Qh, Kh, Vtr, ctx);

  gemm_out_k<<<dim3(Mz / 128, Dz / 128), 256, 0, stream>>>(ctx, Wot, bo, out);
}

// Round 3
// 120.362 us; speedup vs baseline: 1.3210x; 1.2800x over previous
//
#include <hip/hip_runtime.h>
#include <hip/hip_bf16.h>
#include <stdint.h>

#define Bz 2
#define Sz 2048
#define Dz 768
#define Hz 12
#define DHz 64
#define Mz (Bz*Sz)   // 4096

typedef __attribute__((ext_vector_type(4))) float f32x4;
typedef __attribute__((ext_vector_type(8))) short bf16x8;
typedef unsigned short u16;
typedef __attribute__((ext_vector_type(8))) unsigned short u16x8;

__device__ __forceinline__ u16 f2bf(float f) {
  union { float f; uint32_t u; } c; c.f = f;
  uint32_t u = c.u;
  return (u16)((u + 0x7fffu + ((u >> 16) & 1u)) >> 16);
}

#define GLL16(gsrc, ldst) \
  __builtin_amdgcn_global_load_lds((const __attribute__((address_space(1))) void*)(gsrc), \
                                   (__attribute__((address_space(3))) void*)(ldst), 16, 0, 0)

__device__ __forceinline__ f32x4 mfma16(bf16x8 a, bf16x8 b, f32x4 c) {
  return __builtin_amdgcn_mfma_f32_16x16x32_bf16(a, b, c, 0, 0, 0);
}

// ---------------- pre-pass: fp32 -> bf16 (q,k,v fused in one launch) ----------------
__global__ void cvt3_kernel(const float* __restrict__ qa, const float* __restrict__ ka,
                            const float* __restrict__ va,
                            u16* __restrict__ qo, u16* __restrict__ ko, u16* __restrict__ vo,
                            int n8) {
  int i = blockIdx.x * blockDim.x + threadIdx.x;
  if (i >= n8) return;
  int z = blockIdx.y;
  const float* src = (z == 0) ? qa : (z == 1) ? ka : va;
  u16* dst = (z == 0) ? qo : (z == 1) ? ko : vo;
  const float4* s4 = (const float4*)src;
  float4 a = s4[(size_t)i * 2];
  float4 b = s4[(size_t)i * 2 + 1];
  u16x8 o;
  o[0] = f2bf(a.x); o[1] = f2bf(a.y); o[2] = f2bf(a.z); o[3] = f2bf(a.w);
  o[4] = f2bf(b.x); o[5] = f2bf(b.y); o[6] = f2bf(b.z); o[7] = f2bf(b.w);
  *(u16x8*)(dst + (size_t)i * 8) = o;
}

// ---------------- pre-pass: W [K][N] fp32 -> Wt [N][K] bf16 (4 weights fused) ----------------
__global__ void wtrans4_kernel(const float* __restrict__ W0, const float* __restrict__ W1,
                               const float* __restrict__ W2, const float* __restrict__ W3,
                               u16* __restrict__ T0, u16* __restrict__ T1,
                               u16* __restrict__ T2, u16* __restrict__ T3) {
  __shared__ float tile[32][33];
  int z = blockIdx.z;
  const float* W = (z == 0) ? W0 : (z == 1) ? W1 : (z == 2) ? W2 : W3;
  u16* Wt = (z == 0) ? T0 : (z == 1) ? T1 : (z == 2) ? T2 : T3;
  int bx = blockIdx.x * 32, by = blockIdx.y * 32;
  int tx = threadIdx.x & 31, ty = threadIdx.x >> 5;   // 256 threads: ty 0..7
#pragma unroll
  for (int i = 0; i < 32; i += 8)
    tile[ty + i][tx] = W[(size_t)(by + ty + i) * Dz + bx + tx];
  __syncthreads();
#pragma unroll
  for (int i = 0; i < 32; i += 8)
    Wt[(size_t)(bx + ty + i) * Dz + by + tx] = f2bf(tile[tx][ty + i]);
}

// ---------------- GEMM core: C[M][N] = A[M][K] * Wt[N][K]^T + bias ----------------
// mode 0: bf16 out, layout [B,H,S,DH]   (Q, K projections)  (out = (acc+bias)*oscale)
// mode 1: bf16 out, layout [B,H,DH,S]   (V projection, transposed)
// mode 2: fp32 out, layout [M][N]       (final output projection)
__device__ __forceinline__ void gemm_core(
    const u16* __restrict__ A, const u16* __restrict__ Wt,
    const float* __restrict__ bias, void* __restrict__ out, int mode, float oscale,
    u16* As, u16* Bs)
{
  const int tid = threadIdx.x;
  const int wid = tid >> 6, lane = tid & 63;
  const int wm = wid >> 1, wn = wid & 1;
  const int m0 = blockIdx.x * 128, n0 = blockIdx.y * 128;
  const int fq = lane >> 4, fr = lane & 15;

  // staging source offsets (pre-swizzled so linear LDS dest + swizzled read match)
  int aoff[2];
#pragma unroll
  for (int c = 0; c < 2; ++c) {
    int off  = (wid * 2 + c) * 1024 + lane * 16;       // linear byte offset in 8KB tile
    int row  = off >> 6;                               // 64B rows (32 bf16)
    int colb = (off & 63) ^ (((row >> 1) & 3) << 4);   // XOR swizzle, bits 4-5
    aoff[c]  = row * Dz + (colb >> 1);                 // element offset (row stride K=768)
  }

  // fragment read byte-offsets
  int raddr[4], rbaddr[4];
#pragma unroll
  for (int f = 0; f < 4; ++f) {
    int rowA = wm * 64 + f * 16 + fr;
    raddr[f]  = rowA * 64 + ((fq * 16) ^ (((rowA >> 1) & 3) << 4));
    int rowB = wn * 64 + f * 16 + fr;
    rbaddr[f] = rowB * 64 + ((fq * 16) ^ (((rowB >> 1) & 3) << 4));
  }

  f32x4 acc[4][4];
  const f32x4 zero = {0.f, 0.f, 0.f, 0.f};
#pragma unroll
  for (int i = 0; i < 4; ++i)
#pragma unroll
    for (int j = 0; j < 4; ++j) acc[i][j] = zero;

  const u16* Abase = A + (size_t)m0 * Dz;
  const u16* Bbase = Wt + (size_t)n0 * Dz;

  for (int kt = 0; kt < Dz; kt += 32) {
#pragma unroll
    for (int c = 0; c < 2; ++c) {
      GLL16(Abase + kt + aoff[c], (char*)As + (wid * 2 + c) * 1024);
      GLL16(Bbase + kt + aoff[c], (char*)Bs + (wid * 2 + c) * 1024);
    }
    __syncthreads();
    bf16x8 af[4], bf[4];
#pragma unroll
    for (int f = 0; f < 4; ++f) {
      af[f] = *(const bf16x8*)((const char*)As + raddr[f]);
      bf[f] = *(const bf16x8*)((const char*)Bs + rbaddr[f]);
    }
    __builtin_amdgcn_s_setprio(1);
#pragma unroll
    for (int i = 0; i < 4; ++i)
#pragma unroll
      for (int j = 0; j < 4; ++j)
        acc[i][j] = mfma16(af[i], bf[j], acc[i][j]);
    __builtin_amdgcn_s_setprio(0);
    __syncthreads();
  }

  if (mode == 2) {
    float* O = (float*)out;
#pragma unroll
    for (int i = 0; i < 4; ++i) {
      int grow = m0 + wm * 64 + i * 16 + fq * 4;
#pragma unroll
      for (int j = 0; j < 4; ++j) {
        int gcol = n0 + wn * 64 + j * 16 + fr;
        float bv = bias[gcol];
#pragma unroll
        for (int r = 0; r < 4; ++r)
          O[(size_t)(grow + r) * Dz + gcol] = acc[i][j][r] + bv;
      }
    }
  } else {
    u16* O = (u16*)out;
#pragma unroll
    for (int i = 0; i < 4; ++i) {
      int grow = m0 + wm * 64 + i * 16 + fq * 4;
#pragma unroll
      for (int j = 0; j < 4; ++j) {
        int gcol = n0 + wn * 64 + j * 16 + fr;
        float bv = bias[gcol];
        int h = gcol >> 6, dh = gcol & 63;
#pragma unroll
        for (int r = 0; r < 4; ++r) {
          int t = grow + r;
          int b = t >> 11, s = t & 2047;
          float v = (acc[i][j][r] + bv) * oscale;
          if (mode == 0)
            O[((size_t)(b * Hz + h) * Sz + s) * DHz + dh] = f2bf(v);
          else
            O[((size_t)(b * Hz + h) * DHz + dh) * Sz + s] = f2bf(v);
        }
      }
    }
  }
}

// Q is pre-scaled by 1/sqrt(DH) * log2(e) so attention can use raw v_exp_f32 (exp2)
#define QSCALE 0.1803368801111404f   // 0.125 * 1.4426950408889634

__global__ __launch_bounds__(256, 2) void gemm_qkv(
    const u16* __restrict__ qb, const u16* __restrict__ kb, const u16* __restrict__ vb,
    const u16* __restrict__ Wqt, const u16* __restrict__ Wkt, const u16* __restrict__ Wvt,
    const float* __restrict__ bq, const float* __restrict__ bk, const float* __restrict__ bv,
    u16* __restrict__ Qh, u16* __restrict__ Kh, u16* __restrict__ Vt)
{
  __shared__ u16 As[128 * 32];
  __shared__ u16 Bs[128 * 32];
  const u16* A; const u16* W; const float* bias; u16* out; int mode; float osc;
  if (blockIdx.z == 0)      { A = qb; W = Wqt; bias = bq; out = Qh; mode = 0; osc = QSCALE; }
  else if (blockIdx.z == 1) { A = kb; W = Wkt; bias = bk; out = Kh; mode = 0; osc = 1.f; }
  else                      { A = vb; W = Wvt; bias = bv; out = Vt; mode = 1; osc = 1.f; }
  gemm_core(A, W, bias, out, mode, osc, As, Bs);
}

__global__ __launch_bounds__(256, 2) void gemm_out_k(
    const u16* __restrict__ ctx, const u16* __restrict__ Wot,
    const float* __restrict__ bo, float* __restrict__ out)
{
  __shared__ u16 As[128 * 32];
  __shared__ u16 Bs[128 * 32];
  gemm_core(ctx, Wot, bo, (void*)out, 2, 1.f, As, Bs);
}

// ---------------- flash attention, causal ----------------
// grid (B*H, S/64), block 256. bq = 31 - blockIdx.y => globally heaviest-first (LPT).
// Each wave owns 16 q-rows. K/V double-buffered.
__device__ __forceinline__ void stage_kv(const u16* __restrict__ Kg, const u16* __restrict__ Vg,
                                         int kt, u16* Ks, u16* Vs, int wid, int lane) {
#pragma unroll
  for (int c = 0; c < 2; ++c) {
    int off  = (wid * 2 + c) * 1024 + lane * 16;
    int row  = off >> 7;                       // 128B rows (64 bf16)
    int colb = (off & 127) ^ ((row & 7) << 4); // XOR swizzle bits 4-6
    GLL16(Kg + ((size_t)(kt * 64 + row)) * DHz + (colb >> 1), (char*)Ks + (wid * 2 + c) * 1024);
    GLL16(Vg + (size_t)row * Sz + kt * 64 + (colb >> 1),      (char*)Vs + (wid * 2 + c) * 1024);
  }
}

__global__ __launch_bounds__(256, 4) void attn_kernel(
    const u16* __restrict__ Qh, const u16* __restrict__ Kh,
    const u16* __restrict__ Vt, u16* __restrict__ ctx)
{
  __shared__ u16 Ks[2][64 * 64];
  __shared__ u16 Vs[2][64 * 64];
  __shared__ u16 Ps[4 * 16 * 64];
  const int tid = threadIdx.x, wid = tid >> 6, lane = tid & 63;
  const int fq = lane >> 4, fr = lane & 15;
  const int bh = blockIdx.x;
  const int bq = (gridDim.y - 1) - blockIdx.y;   // global LPT: heaviest blocks dispatch first
  const int b = bh / Hz, h = bh % Hz;
  const int qbase = bq * 64 + wid * 16;

  // Q fragments (held for the whole kernel; pre-scaled by QSCALE at projection)
  const u16* Qg = Qh + ((size_t)bh * Sz + qbase) * DHz;
  bf16x8 aq[2];
#pragma unroll
  for (int kk = 0; kk < 2; ++kk)
    aq[kk] = *(const bf16x8*)(Qg + fr * DHz + kk * 32 + fq * 8);

  const f32x4 zero = {0.f, 0.f, 0.f, 0.f};
  f32x4 o[4];
#pragma unroll
  for (int i = 0; i < 4; ++i) o[i] = zero;
  float m_r[4], l_r[4];
#pragma unroll
  for (int r = 0; r < 4; ++r) { m_r[r] = -1e30f; l_r[r] = 0.f; }

  const u16* Kg = Kh + (size_t)bh * Sz * DHz;
  const u16* Vg = Vt + (size_t)bh * DHz * Sz;
  u16* Pw = Ps + wid * 16 * 64;
  const int nkt = bq + 1;

  stage_kv(Kg, Vg, 0, Ks[0], Vs[0], wid, lane);
  int cur = 0;

  for (int kt = 0; kt < nkt; ++kt) {
    __syncthreads();   // buf[cur] staging drained; prev tile's LDS reads complete
    if (kt + 1 < nkt)
      stage_kv(Kg, Vg, kt + 1, Ks[cur ^ 1], Vs[cur ^ 1], wid, lane);

    const char* Kb = (const char*)Ks[cur];
    const char* Vb = (const char*)Vs[cur];

    // S = Q K^T   (already in log2-domain: Q pre-scaled by 0.125*log2e)
    f32x4 s[4];
#pragma unroll
    for (int j = 0; j < 4; ++j) s[j] = zero;
    __builtin_amdgcn_s_setprio(1);
#pragma unroll
    for (int j = 0; j < 4; ++j) {
      int rowK = j * 16 + fr;
#pragma unroll
      for (int kk = 0; kk < 2; ++kk) {
        int cb = (kk * 64 + fq * 16) ^ ((rowK & 7) << 4);
        bf16x8 bk_ = *(const bf16x8*)(Kb + rowK * 128 + cb);
        s[j] = mfma16(aq[kk], bk_, s[j]);
      }
    }
    __builtin_amdgcn_s_setprio(0);

    // causal mask: only the diagonal tile needs it (block-uniform branch)
    if (kt == bq) {
#pragma unroll
      for (int j = 0; j < 4; ++j) {
        int keyg = kt * 64 + j * 16 + fr;
#pragma unroll
        for (int r = 0; r < 4; ++r)
          if (keyg > qbase + fq * 4 + r) s[j][r] = -1e30f;
      }
    }

    // row max (16-lane butterfly within fr groups)
    float mt[4];
#pragma unroll
    for (int r = 0; r < 4; ++r) mt[r] = s[0][r];
#pragma unroll
    for (int j = 1; j < 4; ++j)
#pragma unroll
      for (int r = 0; r < 4; ++r) mt[r] = fmaxf(mt[r], s[j][r]);
#pragma unroll
    for (int msk = 1; msk < 16; msk <<= 1)
#pragma unroll
      for (int r = 0; r < 4; ++r) mt[r] = fmaxf(mt[r], __shfl_xor(mt[r], msk));

    // defer-max (T13, THR=8 in exp2 domain): rescale only when max grew enough
    int nd = 0;
#pragma unroll
    for (int r = 0; r < 4; ++r) nd |= (mt[r] > m_r[r] + 8.f) ? 1 : 0;
    if (__any(nd)) {
#pragma unroll
      for (int r = 0; r < 4; ++r) {
        float mn = fmaxf(m_r[r], mt[r]);
        float alpha = __builtin_amdgcn_exp2f(m_r[r] - mn);
        m_r[r] = mn;
        l_r[r] *= alpha;
#pragma unroll
        for (int i = 0; i < 4; ++i) o[i][r] *= alpha;
      }
    }

    // P = exp2(S - m), write to per-wave LDS (swizzled)
    float rs[4];
#pragma unroll
    for (int r = 0; r < 4; ++r) rs[r] = 0.f;
#pragma unroll
    for (int j = 0; j < 4; ++j) {
#pragma unroll
      for (int r = 0; r < 4; ++r) {
        float e = __builtin_amdgcn_exp2f(s[j][r] - m_r[r]);
        rs[r] += e;
        int qr = fq * 4 + r;
        int key2 = (j * 16 + fr) * 2;
        *(u16*)((char*)Pw + qr * 128 + (key2 ^ ((qr & 7) << 4))) = f2bf(e);
      }
    }
#pragma unroll
    for (int msk = 1; msk < 16; msk <<= 1)
#pragma unroll
      for (int r = 0; r < 4; ++r) rs[r] += __shfl_xor(rs[r], msk);
#pragma unroll
    for (int r = 0; r < 4; ++r) l_r[r] += rs[r];

    // O += P V
    __builtin_amdgcn_s_setprio(1);
#pragma unroll
    for (int kk = 0; kk < 2; ++kk) {
      int cbP = (kk * 64 + fq * 16) ^ ((fr & 7) << 4);
      bf16x8 pa = *(const bf16x8*)((const char*)Pw + fr * 128 + cbP);
#pragma unroll
      for (int fo = 0; fo < 4; ++fo) {
        int rowV = fo * 16 + fr;
        int cbV = (kk * 64 + fq * 16) ^ ((rowV & 7) << 4);
        bf16x8 bv_ = *(const bf16x8*)(Vb + rowV * 128 + cbV);
        o[fo] = mfma16(pa, bv_, o[fo]);
      }
    }
    __builtin_amdgcn_s_setprio(0);
    cur ^= 1;
  }

  // normalize + write ctx [B,S,D] bf16
#pragma unroll
  for (int fo = 0; fo < 4; ++fo) {
    int dh = fo * 16 + fr;
#pragma unroll
    for (int r = 0; r < 4; ++r) {
      int qg = qbase + fq * 4 + r;
      ctx[((size_t)b * Sz + qg) * Dz + h * DHz + dh] = f2bf(o[fo][r] / l_r[r]);
    }
  }
}

// ---------------- launch ----------------
extern "C" void kernel_launch(void* const* d_in, const int* in_sizes, int n_in,
                              void* d_out, int out_size, void* d_ws, size_t ws_size,
                              hipStream_t stream) {
  const float* q  = (const float*)d_in[0];
  const float* k  = (const float*)d_in[1];
  const float* v  = (const float*)d_in[2];
  const float* Wq = (const float*)d_in[3];
  const float* bq = (const float*)d_in[4];
  const float* Wk = (const float*)d_in[5];
  const float* bk = (const float*)d_in[6];
  const float* Wv = (const float*)d_in[7];
  const float* bv = (const float*)d_in[8];
  const float* Wo = (const float*)d_in[9];
  const float* bo = (const float*)d_in[10];
  float* out = (float*)d_out;

  char* ws = (char*)d_ws;
  size_t off = 0;
  auto alloc = [&](size_t bytes) {
    void* p = ws + off;
    off += (bytes + 255) & ~(size_t)255;
    return p;
  };
  u16* qb  = (u16*)alloc((size_t)Mz * Dz * 2);
  u16* kb  = (u16*)alloc((size_t)Mz * Dz * 2);
  u16* vb  = (u16*)alloc((size_t)Mz * Dz * 2);
  u16* Wqt = (u16*)alloc((size_t)Dz * Dz * 2);
  u16* Wkt = (u16*)alloc((size_t)Dz * Dz * 2);
  u16* Wvt = (u16*)alloc((size_t)Dz * Dz * 2);
  u16* Wot = (u16*)alloc((size_t)Dz * Dz * 2);
  u16* Qh  = (u16*)alloc((size_t)Bz * Hz * Sz * DHz * 2);
  u16* Kh  = (u16*)alloc((size_t)Bz * Hz * Sz * DHz * 2);
  u16* Vtr = (u16*)alloc((size_t)Bz * Hz * DHz * Sz * 2);
  u16* ctx = (u16*)alloc((size_t)Mz * Dz * 2);

  int n8 = Mz * Dz / 8;
  int cblk = (n8 + 255) / 256;
  cvt3_kernel<<<dim3(cblk, 3), 256, 0, stream>>>(q, k, v, qb, kb, vb, n8);

  wtrans4_kernel<<<dim3(Dz / 32, Dz / 32, 4), 256, 0, stream>>>(
      Wq, Wk, Wv, Wo, Wqt, Wkt, Wvt, Wot);

  gemm_qkv<<<dim3(Mz / 128, Dz / 128, 3), 256, 0, stream>>>(
      qb, kb, vb, Wqt, Wkt, Wvt, bq, bk, bv, Qh, Kh, Vtr);

  attn_kernel<<<dim3(Bz * Hz, Sz / 64), 256, 0, stream>>>(Qh, Kh, Vtr, ctx);

  gemm_out_k<<<dim3(Mz / 128, Dz / 128), 256, 0, stream>>>(ctx, Wot, bo, out);
}